// Round 1
// baseline (613.422 us; speedup 1.0000x reference)
//
#include <hip/hip_runtime.h>

typedef short s8v __attribute__((ext_vector_type(8)));
typedef float f4v __attribute__((ext_vector_type(4)));

union F8 { int4 i; s8v s; };

__device__ __forceinline__ short f2bf(float f){
  union {float f; unsigned u;} v; v.f = f;
  unsigned r = (v.u + 0x7FFFu + ((v.u >> 16) & 1u)) >> 16;
  return (short)r;
}

#define MFMA(a,b,c) __builtin_amdgcn_mfma_f32_16x16x32_bf16((a),(b),(c),0,0,0)

// ---- workspace layout ----
// [0)            : w_qkv bf16, padded to 304 rows x 96  (58368 B)
// [58368)        : w_proj bf16, 96 x 96                 (18432 B)
// [76800)        : stats, 192 floats (sum[96], sumsq[96])
// [1<<20)        : attention output, fp32, 8*96*256*256 (201326592 B)
#define WS_W2_OFF   58368
#define WS_ST_OFF   76800
#define WS_OUT_OFF  (1u<<20)

__global__ void prep_kernel(const float* __restrict__ wqkv, const float* __restrict__ wproj,
                            unsigned short* __restrict__ w1, unsigned short* __restrict__ w2,
                            float* __restrict__ stats){
  int i = blockIdx.x * 256 + threadIdx.x;
  for (int j = i; j < 304*96; j += gridDim.x * 256){
    int row = j / 96, c = j - row * 96;
    float v = (row < 288) ? wqkv[row * 96 + c] : 0.f;
    w1[j] = (unsigned short)f2bf(v);
  }
  for (int j = i; j < 96*96; j += gridDim.x * 256)
    w2[j] = (unsigned short)f2bf(wproj[j]);
  if (i < 192) stats[i] = 0.f;
}

// One block per 16x16 window. QKV via MFMA, attention via MFMA with identity tricks.
__global__ __launch_bounds__(256) void attn_kernel(const float* __restrict__ x,
                                                   const unsigned short* __restrict__ w1,
                                                   float* __restrict__ outp){
  __shared__ short ks[16*264];   // k_norm bf16 [dd][token], row 15 = ones
  __shared__ short vs[16*264];   // v bf16 [dd][token], row 15 = ones
  __shared__ short qsT[256*32];  // q_norm bf16 [token][dd], col 12 = 1.0, 13..31 = 0
  __shared__ short kvT[16*32];   // kv^T bf16 [c][m]; row 12 = ksum; col 12 = vsum

  const int tid  = threadIdx.x;
  const int lane = tid & 63, wave = tid >> 6;
  const int quad = lane >> 4, col = lane & 15;
  const int wx = blockIdx.x, wy = blockIdx.y, b = blockIdx.z;
  const int h0 = wy * 16, w0 = wx * 16;

  // init constant LDS regions
  for (int i = tid; i < 4*264; i += 256){
    int r = i / 264; int cc = i - r * 264; r += 12;
    short v = (r == 15) ? (short)0x3F80 : (short)0;
    ks[r*264 + cc] = v; vs[r*264 + cc] = v;
  }
  for (int i = tid; i < 256*32; i += 256){
    int m = i & 31;
    qsT[i] = (m == 12) ? (short)0x3F80 : (short)0;
  }
  for (int i = tid; i < 16*32; i += 256) kvT[i] = 0;

  // B fragments: X window (K=channel, N=token), loaded once, reused for all heads
  const float* xb = x + ((size_t)b * 96 << 16);
  s8v Bf[4][3];
  #pragma unroll
  for (int jt = 0; jt < 4; ++jt){
    int t0 = wave * 64 + jt * 16;
    const float* px = xb + (size_t)(h0 + (t0 >> 4)) * 256 + (w0 + col);
    #pragma unroll
    for (int kt = 0; kt < 3; ++kt){
      F8 f;
      #pragma unroll
      for (int j = 0; j < 8; ++j){
        int c = kt * 32 + quad * 8 + j;
        f.s[j] = f2bf(px[(size_t)c << 16]);
      }
      Bf[jt][kt] = f.s;
    }
  }

  for (int h = 0; h < 8; ++h){
    // A fragments: w_qkv rows for this head (q/k/v chunks of 12, padded to 16)
    s8v Af[3][3];
    #pragma unroll
    for (int mi = 0; mi < 3; ++mi){
      int row = mi * 96 + h * 12 + col;
      const unsigned short* pw = w1 + row * 96 + quad * 8;
      #pragma unroll
      for (int kt = 0; kt < 3; ++kt){
        F8 f; f.i = *(const int4*)(pw + kt * 32);
        Af[mi][kt] = f.s;
      }
    }
    f4v acc[3][4];
    #pragma unroll
    for (int mi = 0; mi < 3; ++mi)
      #pragma unroll
      for (int jt = 0; jt < 4; ++jt){
        f4v a = {0.f, 0.f, 0.f, 0.f};
        #pragma unroll
        for (int kt = 0; kt < 3; ++kt) a = MFMA(Af[mi][kt], Bf[jt][kt], a);
        acc[mi][jt] = a;
      }

    // epilogue: l2norm q,k; scatter q_norm/k_norm/v into LDS
    #pragma unroll
    for (int jt = 0; jt < 4; ++jt){
      int t = wave * 64 + jt * 16 + col;
      {
        f4v q = acc[0][jt];
        float s = (quad < 3) ? (q[0]*q[0] + q[1]*q[1] + q[2]*q[2] + q[3]*q[3]) : 0.f;
        s += __shfl_xor(s, 16, 64); s += __shfl_xor(s, 32, 64);
        float rq = rsqrtf(s);
        if (quad < 3){
          short4 pk; pk.x = f2bf(q[0]*rq); pk.y = f2bf(q[1]*rq); pk.z = f2bf(q[2]*rq); pk.w = f2bf(q[3]*rq);
          *(short4*)&qsT[t * 32 + quad * 4] = pk;
        }
      }
      {
        f4v k = acc[1][jt];
        float s = (quad < 3) ? (k[0]*k[0] + k[1]*k[1] + k[2]*k[2] + k[3]*k[3]) : 0.f;
        s += __shfl_xor(s, 16, 64); s += __shfl_xor(s, 32, 64);
        float rk = rsqrtf(s);
        f4v vv = acc[2][jt];
        if (quad < 3){
          #pragma unroll
          for (int r = 0; r < 4; ++r){
            ks[(quad*4 + r) * 264 + t] = f2bf(k[r] * rk);
            vs[(quad*4 + r) * 264 + t] = f2bf(vv[r]);
          }
        }
      }
    }
    __syncthreads();  // ks/vs/qsT complete

    if (wave == 0){
      // kv[m][c] = sum_n k_norm[m][n] * v[c][n]; row15-of-ones => kv[15][c]=vsum, kv[m][15]=ksum
      f4v kv = {0.f, 0.f, 0.f, 0.f};
      #pragma unroll
      for (int kk = 0; kk < 8; ++kk){
        F8 a, bb;
        a.i  = *(const int4*)&ks[col * 264 + kk * 32 + quad * 8];
        bb.i = *(const int4*)&vs[col * 264 + kk * 32 + quad * 8];
        kv = MFMA(a.s, bb.s, kv);
      }
      int c = col;
      if (c != 12){                      // c==12 column is zeros; row 12 reserved for ksum
        int row = (c == 15) ? 12 : c;    // redirect ksum column into kvT row 12
        if (quad < 3){
          short4 pk; pk.x = f2bf(kv[0]); pk.y = f2bf(kv[1]); pk.z = f2bf(kv[2]); pk.w = f2bf(kv[3]);
          *(short4*)&kvT[row * 32 + quad * 4] = pk;
        } else {
          short4 pk; pk.x = (c == 15) ? (short)0 : f2bf(kv[3]); pk.y = 0; pk.z = 0; pk.w = 0;
          *(short4*)&kvT[row * 32 + 12] = pk;   // kvT[c][12] = vsum[c]
        }
      }
    }
    __syncthreads();  // kvT complete

    {
      F8 af; af.i = *(const int4*)&kvT[col * 32 + quad * 8];   // A[c][m']
      #pragma unroll
      for (int jt = 0; jt < 4; ++jt){
        int t0 = wave * 64 + jt * 16;
        F8 bq; bq.i = *(const int4*)&qsT[(t0 + col) * 32 + quad * 8];  // B[m'][t]
        f4v z = {0.f, 0.f, 0.f, 0.f};
        f4v d2 = MFMA(af.s, bq.s, z);
        // row 12 of D2 = q.ksum (tailor denom term); col-12 identity added vsum
        float dot = __shfl(d2[0], 48 + col, 64);
        float tl = 1.f / (256.f + dot);
        if (quad < 3){
          float* po = outp + ((size_t)(b * 96 + h * 12 + quad * 4) << 16)
                      + (size_t)(h0 + (t0 >> 4)) * 256 + (w0 + col);
          #pragma unroll
          for (int r = 0; r < 4; ++r) po[(size_t)r << 16] = d2[r] * tl;
        }
      }
    }
    __syncthreads();  // protect LDS before next head overwrites
  }
}

// proj GEMM (96x96) per 256-pixel image row + per-channel sum/sumsq partials
__global__ __launch_bounds__(256) void proj_kernel(const float* __restrict__ outp,
                                                   const unsigned short* __restrict__ w2,
                                                   float* __restrict__ y,
                                                   float* __restrict__ stats){
  __shared__ float sld[192];
  const int tid = threadIdx.x;
  if (tid < 192) sld[tid] = 0.f;
  __syncthreads();
  const int lane = tid & 63, wave = tid >> 6;
  const int quad = lane >> 4, col = lane & 15;
  const int hrow = blockIdx.x, b = blockIdx.y;

  const float* ob = outp + ((size_t)b * 96 << 16) + (size_t)hrow * 256;
  s8v Bf[4][3];
  #pragma unroll
  for (int jt = 0; jt < 4; ++jt){
    int n0 = wave * 64 + jt * 16;
    const float* px = ob + n0 + col;
    #pragma unroll
    for (int kt = 0; kt < 3; ++kt){
      F8 f;
      #pragma unroll
      for (int j = 0; j < 8; ++j){
        int c = kt * 32 + quad * 8 + j;
        f.s[j] = f2bf(px[(size_t)c << 16]);
      }
      Bf[jt][kt] = f.s;
    }
  }
  float* yb = y + ((size_t)b * 96 << 16) + (size_t)hrow * 256;
  #pragma unroll
  for (int mt = 0; mt < 6; ++mt){
    s8v Af[3];
    #pragma unroll
    for (int kt = 0; kt < 3; ++kt){
      F8 f; f.i = *(const int4*)(w2 + (mt * 16 + col) * 96 + kt * 32 + quad * 8);
      Af[kt] = f.s;
    }
    float rs[4] = {0.f,0.f,0.f,0.f}, rss[4] = {0.f,0.f,0.f,0.f};
    #pragma unroll
    for (int jt = 0; jt < 4; ++jt){
      int n0 = wave * 64 + jt * 16;
      f4v a = {0.f, 0.f, 0.f, 0.f};
      #pragma unroll
      for (int kt = 0; kt < 3; ++kt) a = MFMA(Af[kt], Bf[jt][kt], a);
      float* pyo = yb + ((size_t)(mt * 16 + quad * 4) << 16) + n0 + col;
      #pragma unroll
      for (int r = 0; r < 4; ++r){
        float v = a[r];
        pyo[(size_t)r << 16] = v;
        rs[r] += v; rss[r] += v * v;
      }
    }
    #pragma unroll
    for (int r = 0; r < 4; ++r){
      float a1 = rs[r], a2 = rss[r];
      a1 += __shfl_xor(a1, 1, 64); a2 += __shfl_xor(a2, 1, 64);
      a1 += __shfl_xor(a1, 2, 64); a2 += __shfl_xor(a2, 2, 64);
      a1 += __shfl_xor(a1, 4, 64); a2 += __shfl_xor(a2, 4, 64);
      a1 += __shfl_xor(a1, 8, 64); a2 += __shfl_xor(a2, 8, 64);
      if (col == 0){
        int o = mt * 16 + quad * 4 + r;
        atomicAdd(&sld[o], a1);
        atomicAdd(&sld[96 + o], a2);
      }
    }
  }
  __syncthreads();
  if (tid < 192) atomicAdd(&stats[tid], sld[tid]);
}

// BN normalize in place
__global__ __launch_bounds__(256) void bn_kernel(float* __restrict__ y,
                                                 const float* __restrict__ stats,
                                                 const float* __restrict__ gamma,
                                                 const float* __restrict__ beta){
  const int qq = blockIdx.x, c = blockIdx.y, b = blockIdx.z;
  const float invN = 1.f / 524288.f;
  float s = stats[c], ss = stats[96 + c];
  float mean = s * invN;
  float var  = ss * invN - mean * mean;
  float sc = gamma[c] * rsqrtf(var + 1e-5f);
  float sh = beta[c] - mean * sc;
  float4* p = (float4*)(y + ((size_t)(b * 96 + c) << 16) + (size_t)qq * 16384);
  int tid = threadIdx.x;
  #pragma unroll
  for (int i = 0; i < 16; ++i){
    float4 v = p[tid + i * 256];
    v.x = v.x * sc + sh; v.y = v.y * sc + sh; v.z = v.z * sc + sh; v.w = v.w * sc + sh;
    p[tid + i * 256] = v;
  }
}

extern "C" void kernel_launch(void* const* d_in, const int* in_sizes, int n_in,
                              void* d_out, int out_size, void* d_ws, size_t ws_size,
                              hipStream_t stream){
  const float* x     = (const float*)d_in[0];
  const float* wqkv  = (const float*)d_in[1];
  const float* wproj = (const float*)d_in[2];
  const float* gamma = (const float*)d_in[3];
  const float* beta  = (const float*)d_in[4];
  char* ws = (char*)d_ws;
  unsigned short* w1 = (unsigned short*)(ws);
  unsigned short* w2 = (unsigned short*)(ws + WS_W2_OFF);
  float* stats = (float*)(ws + WS_ST_OFF);
  float* outp  = (float*)(ws + WS_OUT_OFF);
  float* y = (float*)d_out;

  hipLaunchKernelGGL(prep_kernel, dim3(64), dim3(256), 0, stream, wqkv, wproj, w1, w2, stats);
  hipLaunchKernelGGL(attn_kernel, dim3(16, 16, 8), dim3(256), 0, stream, x, w1, outp);
  hipLaunchKernelGGL(proj_kernel, dim3(256, 8), dim3(256), 0, stream, outp, w2, y, stats);
  hipLaunchKernelGGL(bn_kernel, dim3(4, 96, 8), dim3(256), 0, stream, y, stats, gamma, beta);
}

// Round 2
// 606.930 us; speedup vs baseline: 1.0107x; 1.0107x over previous
//
#include <hip/hip_runtime.h>

typedef short s8v __attribute__((ext_vector_type(8)));
typedef float f4v __attribute__((ext_vector_type(4)));

union F8 { int4 i; s8v s; };

__device__ __forceinline__ short f2bf(float f){
  union {float f; unsigned u;} v; v.f = f;
  unsigned r = (v.u + 0x7FFFu + ((v.u >> 16) & 1u)) >> 16;
  return (short)r;
}

#define MFMA(a,b,c) __builtin_amdgcn_mfma_f32_16x16x32_bf16((a),(b),(c),0,0,0)

// ---- workspace layout ----
// [0)            : w_qkv bf16, padded to 304 rows x 96  (58368 B)
// [58368)        : w_proj bf16, 96 x 96                 (18432 B)
// [76800)        : stats, 192 floats (sum[96], sumsq[96])
// [1<<20)        : attention output, bf16 channel-last [b][pix][96] (100.7 MB)
#define WS_W2_OFF   58368
#define WS_ST_OFF   76800
#define WS_OUT_OFF  (1u<<20)

__global__ void prep_kernel(const float* __restrict__ wqkv, const float* __restrict__ wproj,
                            unsigned short* __restrict__ w1, unsigned short* __restrict__ w2,
                            float* __restrict__ stats){
  int i = blockIdx.x * 256 + threadIdx.x;
  for (int j = i; j < 304*96; j += gridDim.x * 256){
    int row = j / 96, c = j - row * 96;
    float v = (row < 288) ? wqkv[row * 96 + c] : 0.f;
    w1[j] = (unsigned short)f2bf(v);
  }
  for (int j = i; j < 96*96; j += gridDim.x * 256)
    w2[j] = (unsigned short)f2bf(wproj[j]);
  if (i < 192) stats[i] = 0.f;
}

// One block per 16x16 window. Double-buffered ks/vs: ONE barrier per head.
// kv computed redundantly by all waves; kv->A-frag transpose via shuffles.
// qsT is wave-private (each wave reads only its own 64 token rows).
__global__ __launch_bounds__(256) void attn_kernel(const float* __restrict__ x,
                                                   const unsigned short* __restrict__ w1,
                                                   short* __restrict__ outp){
  __shared__ short ks[2][16*264];   // k_norm bf16 [dd][token], rows 12..14 = 0, 15 = ones
  __shared__ short vs[2][16*264];   // v bf16, same shape/constants
  __shared__ short qsT[256*40];     // q_norm bf16 [token][kdim]; col 12 = 1.0, 13..39 = 0

  const int tid  = threadIdx.x;
  const int lane = tid & 63, wave = tid >> 6;
  const int quad = lane >> 4, col = lane & 15;
  const int wx = blockIdx.x, wy = blockIdx.y, b = blockIdx.z;
  const int h0 = wy * 16, w0 = wx * 16;

  // init constant LDS regions (rows 12..15 of ks/vs both buffers; qsT cols 12..39)
  for (int i = tid; i < 2*4*264; i += 256){
    int buf = i / (4*264), j = i % (4*264);
    int r = 12 + j / 264, cc = j % 264;
    short v = (r == 15) ? (short)0x3F80 : (short)0;
    ks[buf][r*264 + cc] = v; vs[buf][r*264 + cc] = v;
  }
  for (int i = tid; i < 256*40; i += 256)
    qsT[i] = ((i % 40) == 12) ? (short)0x3F80 : (short)0;

  // B fragments: X window (K=channel, N=token), loaded once, reused for all heads
  const float* xb = x + ((size_t)b * 96 << 16);
  s8v Bf[4][3];
  #pragma unroll
  for (int jt = 0; jt < 4; ++jt){
    int t0 = wave * 64 + jt * 16;
    const float* px = xb + (size_t)(h0 + (t0 >> 4)) * 256 + (w0 + col);
    #pragma unroll
    for (int kt = 0; kt < 3; ++kt){
      F8 f;
      #pragma unroll
      for (int j = 0; j < 8; ++j){
        int c = kt * 32 + quad * 8 + j;
        f.s[j] = f2bf(px[(size_t)c << 16]);
      }
      Bf[jt][kt] = f.s;
    }
  }

  for (int h = 0; h < 8; ++h){
    const int p = h & 1;
    // ---- Q: MFMA + l2norm -> qsT (wave-private rows, no barrier needed) ----
    {
      s8v Aq[3];
      #pragma unroll
      for (int kt = 0; kt < 3; ++kt){
        F8 f; f.i = *(const int4*)(w1 + (h*12 + col) * 96 + kt*32 + quad*8);
        Aq[kt] = f.s;
      }
      #pragma unroll
      for (int jt = 0; jt < 4; ++jt){
        f4v a = {0.f,0.f,0.f,0.f};
        #pragma unroll
        for (int kt = 0; kt < 3; ++kt) a = MFMA(Aq[kt], Bf[jt][kt], a);
        float s = (quad < 3) ? (a[0]*a[0] + a[1]*a[1] + a[2]*a[2] + a[3]*a[3]) : 0.f;
        s += __shfl_xor(s, 16, 64); s += __shfl_xor(s, 32, 64);
        float rq = rsqrtf(s);
        if (quad < 3){
          int t = wave*64 + jt*16 + col;
          short4 pk; pk.x = f2bf(a[0]*rq); pk.y = f2bf(a[1]*rq); pk.z = f2bf(a[2]*rq); pk.w = f2bf(a[3]*rq);
          *(short4*)&qsT[t*40 + quad*4] = pk;
        }
      }
    }
    // ---- K: MFMA + l2norm -> ks scatter ----
    {
      s8v Ak[3];
      #pragma unroll
      for (int kt = 0; kt < 3; ++kt){
        F8 f; f.i = *(const int4*)(w1 + (96 + h*12 + col) * 96 + kt*32 + quad*8);
        Ak[kt] = f.s;
      }
      #pragma unroll
      for (int jt = 0; jt < 4; ++jt){
        f4v a = {0.f,0.f,0.f,0.f};
        #pragma unroll
        for (int kt = 0; kt < 3; ++kt) a = MFMA(Ak[kt], Bf[jt][kt], a);
        float s = (quad < 3) ? (a[0]*a[0] + a[1]*a[1] + a[2]*a[2] + a[3]*a[3]) : 0.f;
        s += __shfl_xor(s, 16, 64); s += __shfl_xor(s, 32, 64);
        float rk = rsqrtf(s);
        if (quad < 3){
          int t = wave*64 + jt*16 + col;
          #pragma unroll
          for (int r = 0; r < 4; ++r) ks[p][(quad*4 + r)*264 + t] = f2bf(a[r]*rk);
        }
      }
    }
    // ---- V: MFMA -> vs scatter ----
    {
      s8v Av[3];
      #pragma unroll
      for (int kt = 0; kt < 3; ++kt){
        F8 f; f.i = *(const int4*)(w1 + (192 + h*12 + col) * 96 + kt*32 + quad*8);
        Av[kt] = f.s;
      }
      #pragma unroll
      for (int jt = 0; jt < 4; ++jt){
        f4v a = {0.f,0.f,0.f,0.f};
        #pragma unroll
        for (int kt = 0; kt < 3; ++kt) a = MFMA(Av[kt], Bf[jt][kt], a);
        if (quad < 3){
          int t = wave*64 + jt*16 + col;
          #pragma unroll
          for (int r = 0; r < 4; ++r) vs[p][(quad*4 + r)*264 + t] = f2bf(a[r]);
        }
      }
    }
    __syncthreads();   // the ONE barrier per head: ks/vs buffer p complete

    // ---- kv (all waves, redundant): kv[m][c] = sum_n ks[m][n] vs[c][n] ----
    f4v kvv = {0.f,0.f,0.f,0.f};
    #pragma unroll
    for (int kk = 0; kk < 8; ++kk){
      F8 a, bv;
      a.i  = *(const int4*)&ks[p][col*264 + kk*32 + quad*8];
      bv.i = *(const int4*)&vs[p][col*264 + kk*32 + quad*8];
      kvv = MFMA(a.s, bv.s, kvv);
    }
    // kvv[r] = kv[quad*4+r][col]. Build A-frag A[c'][k]: k<=11 -> kv[k][cc];
    // k==12 -> kv[15][cc] (vsum; for c'==12 it's kv[15][15]=256); k>=13 -> 0.
    F8 fa;
    {
      int cc = (col == 12) ? 15 : col;
      int l0 = ((quad << 1) << 4) | cc;          // src lanes for k>>2 == 2*quad
      int l1 = (((quad << 1) + 1) << 4) | cc;    // src lanes for k>>2 == 2*quad+1
      float v;
      v = __shfl(kvv[0], l0 & 63, 64); fa.s[0] = f2bf((quad < 2) ? v : 0.f);
      v = __shfl(kvv[1], l0 & 63, 64); fa.s[1] = f2bf((quad < 2) ? v : 0.f);
      v = __shfl(kvv[2], l0 & 63, 64); fa.s[2] = f2bf((quad < 2) ? v : 0.f);
      v = __shfl(kvv[3], l0 & 63, 64); fa.s[3] = f2bf((quad < 2) ? v : 0.f);
      float v0  = __shfl(kvv[0], l1 & 63, 64);
      float v15 = __shfl(kvv[3], 48 | cc, 64);
      fa.s[4] = f2bf((quad == 0) ? v0 : ((quad == 1) ? v15 : 0.f));
      v = __shfl(kvv[1], l1 & 63, 64); fa.s[5] = f2bf((quad == 0) ? v : 0.f);
      v = __shfl(kvv[2], l1 & 63, 64); fa.s[6] = f2bf((quad == 0) ? v : 0.f);
      v = __shfl(kvv[3], l1 & 63, 64); fa.s[7] = f2bf((quad == 0) ? v : 0.f);
    }
    // ---- final: D2 = kvT x qhat; row 12 = denominator (includes the +256) ----
    #pragma unroll
    for (int jt = 0; jt < 4; ++jt){
      int t0 = wave*64 + jt*16;
      F8 bq; bq.i = *(const int4*)&qsT[(t0 + col)*40 + quad*8];
      f4v z = {0.f,0.f,0.f,0.f};
      f4v d2 = MFMA(fa.s, bq.s, z);
      float dot = __shfl(d2[0], 48 + col, 64);
      float tl = 1.f / dot;
      if (quad < 3){
        int pix = (h0 + (t0 >> 4)) * 256 + (w0 + col);
        short* po = outp + ((size_t)(b << 16) + pix) * 96 + h*12 + quad*4;
        short4 pk; pk.x = f2bf(d2[0]*tl); pk.y = f2bf(d2[1]*tl); pk.z = f2bf(d2[2]*tl); pk.w = f2bf(d2[3]*tl);
        *(short4*)po = pk;
      }
    }
    // no trailing barrier: next head writes the other ks/vs buffer; qsT is wave-private
  }
}

// proj GEMM (96x96) per 256-pixel image row; B-frags loaded directly as int4 from
// channel-last bf16 outp (no conversion, no LDS). Also accumulates BN stats.
__global__ __launch_bounds__(256) void proj_kernel(const short* __restrict__ outp,
                                                   const unsigned short* __restrict__ w2,
                                                   float* __restrict__ y,
                                                   float* __restrict__ stats){
  __shared__ float sld[192];
  const int tid = threadIdx.x;
  if (tid < 192) sld[tid] = 0.f;
  __syncthreads();
  const int lane = tid & 63, wave = tid >> 6;
  const int quad = lane >> 4, col = lane & 15;
  const int hrow = blockIdx.x, b = blockIdx.y;

  const size_t pixbase = (size_t)(b << 16) + (size_t)hrow * 256;
  s8v Bf[4][3];
  #pragma unroll
  for (int jt = 0; jt < 4; ++jt){
    int n0 = wave*64 + jt*16;
    const short* pb = outp + (pixbase + n0 + col) * 96 + quad*8;
    #pragma unroll
    for (int kt = 0; kt < 3; ++kt){
      F8 f; f.i = *(const int4*)(pb + kt*32);
      Bf[jt][kt] = f.s;
    }
  }
  float* yb = y + ((size_t)(b*96) << 16) + (size_t)hrow * 256;
  #pragma unroll
  for (int mt = 0; mt < 6; ++mt){
    s8v Af[3];
    #pragma unroll
    for (int kt = 0; kt < 3; ++kt){
      F8 f; f.i = *(const int4*)(w2 + (mt*16 + col)*96 + kt*32 + quad*8);
      Af[kt] = f.s;
    }
    float rs[4] = {0.f,0.f,0.f,0.f}, rss[4] = {0.f,0.f,0.f,0.f};
    #pragma unroll
    for (int jt = 0; jt < 4; ++jt){
      int n0 = wave*64 + jt*16;
      f4v a = {0.f,0.f,0.f,0.f};
      #pragma unroll
      for (int kt = 0; kt < 3; ++kt) a = MFMA(Af[kt], Bf[jt][kt], a);
      float* pyo = yb + ((size_t)(mt*16 + quad*4) << 16) + n0 + col;
      #pragma unroll
      for (int r = 0; r < 4; ++r){
        float v = a[r];
        pyo[(size_t)r << 16] = v;
        rs[r] += v; rss[r] += v * v;
      }
    }
    #pragma unroll
    for (int r = 0; r < 4; ++r){
      float a1 = rs[r], a2 = rss[r];
      a1 += __shfl_xor(a1, 1, 64); a2 += __shfl_xor(a2, 1, 64);
      a1 += __shfl_xor(a1, 2, 64); a2 += __shfl_xor(a2, 2, 64);
      a1 += __shfl_xor(a1, 4, 64); a2 += __shfl_xor(a2, 4, 64);
      a1 += __shfl_xor(a1, 8, 64); a2 += __shfl_xor(a2, 8, 64);
      if (col == 0){
        int o = mt*16 + quad*4 + r;
        atomicAdd(&sld[o], a1);
        atomicAdd(&sld[96 + o], a2);
      }
    }
  }
  __syncthreads();
  if (tid < 192) atomicAdd(&stats[tid], sld[tid]);
}

// BN normalize in place
__global__ __launch_bounds__(256) void bn_kernel(float* __restrict__ y,
                                                 const float* __restrict__ stats,
                                                 const float* __restrict__ gamma,
                                                 const float* __restrict__ beta){
  const int qq = blockIdx.x, c = blockIdx.y, b = blockIdx.z;
  const float invN = 1.f / 524288.f;
  float s = stats[c], ss = stats[96 + c];
  float mean = s * invN;
  float var  = ss * invN - mean * mean;
  float sc = gamma[c] * rsqrtf(var + 1e-5f);
  float sh = beta[c] - mean * sc;
  float4* p = (float4*)(y + ((size_t)(b * 96 + c) << 16) + (size_t)qq * 16384);
  int tid = threadIdx.x;
  #pragma unroll
  for (int i = 0; i < 16; ++i){
    float4 v = p[tid + i * 256];
    v.x = v.x * sc + sh; v.y = v.y * sc + sh; v.z = v.z * sc + sh; v.w = v.w * sc + sh;
    p[tid + i * 256] = v;
  }
}

extern "C" void kernel_launch(void* const* d_in, const int* in_sizes, int n_in,
                              void* d_out, int out_size, void* d_ws, size_t ws_size,
                              hipStream_t stream){
  const float* x     = (const float*)d_in[0];
  const float* wqkv  = (const float*)d_in[1];
  const float* wproj = (const float*)d_in[2];
  const float* gamma = (const float*)d_in[3];
  const float* beta  = (const float*)d_in[4];
  char* ws = (char*)d_ws;
  unsigned short* w1 = (unsigned short*)(ws);
  unsigned short* w2 = (unsigned short*)(ws + WS_W2_OFF);
  float* stats = (float*)(ws + WS_ST_OFF);
  short* outp  = (short*)(ws + WS_OUT_OFF);
  float* y = (float*)d_out;

  hipLaunchKernelGGL(prep_kernel, dim3(64), dim3(256), 0, stream, wqkv, wproj, w1, w2, stats);
  hipLaunchKernelGGL(attn_kernel, dim3(16, 16, 8), dim3(256), 0, stream, x, w1, outp);
  hipLaunchKernelGGL(proj_kernel, dim3(256, 8), dim3(256), 0, stream, outp, w2, y, stats);
  hipLaunchKernelGGL(bn_kernel, dim3(4, 96, 8), dim3(256), 0, stream, y, stats, gamma, beta);
}

// Round 3
// 542.366 us; speedup vs baseline: 1.1310x; 1.1190x over previous
//
#include <hip/hip_runtime.h>

typedef short s8v __attribute__((ext_vector_type(8)));
typedef float f4v __attribute__((ext_vector_type(4)));

union F8 { int4 i; s8v s; };
union F8L { long long l[2]; s8v s; };

__device__ __forceinline__ short f2bf(float f){
  union {float f; unsigned u;} v; v.f = f;
  unsigned r = (v.u + 0x7FFFu + ((v.u >> 16) & 1u)) >> 16;
  return (short)r;
}

#define MFMA(a,b,c) __builtin_amdgcn_mfma_f32_16x16x32_bf16((a),(b),(c),0,0,0)

// ---- workspace layout ----
// [0)      : w_qkv bf16, padded to 304 rows x 96          (58368 B)
// [58368)  : w_proj bf16, 96 x 128 (K padded per head 12->16) (24576 B)
// [82944)  : stats, 192 floats (sum[96], sumsq[96])
// [1<<20)  : attention out, bf16 HEAD-MAJOR [b*8+h][pix][12]  (100.7 MB)
#define WS_W2_OFF   58368
#define WS_ST_OFF   82944
#define WS_OUT_OFF  (1u<<20)

__global__ void prep_kernel(const float* __restrict__ wqkv, const float* __restrict__ wproj,
                            unsigned short* __restrict__ w1, unsigned short* __restrict__ w2p,
                            float* __restrict__ stats){
  int i = blockIdx.x * 256 + threadIdx.x;
  for (int j = i; j < 304*96; j += gridDim.x * 256){
    int row = j / 96, c = j - row * 96;
    float v = (row < 288) ? wqkv[row * 96 + c] : 0.f;
    w1[j] = (unsigned short)f2bf(v);
  }
  for (int j = i; j < 96*128; j += gridDim.x * 256){
    int o = j >> 7, c = j & 127, h = c >> 4, ii = c & 15;
    float v = (ii < 12) ? wproj[o * 96 + h * 12 + ii] : 0.f;
    w2p[j] = (unsigned short)f2bf(v);
  }
  if (i < 192) stats[i] = 0.f;
}

// One block per 16x16 window. Double-buffered ks/vs (33.8 KB LDS -> 4 blocks/CU).
// q-hat B-fragment built by in-register shuffle transpose (no qsT LDS).
// One barrier per head. Output head-major bf16 [b*8+h][pix][12].
__global__ __launch_bounds__(256,4) void attn_kernel(const float* __restrict__ x,
                                                     const unsigned short* __restrict__ w1,
                                                     short* __restrict__ outp){
  __shared__ short ks[2][16*264];   // k_norm bf16 [dd][token], rows 12..14 = 0, 15 = ones
  __shared__ short vs[2][16*264];   // v bf16, same shape/constants

  const int tid  = threadIdx.x;
  const int lane = tid & 63, wave = tid >> 6;
  const int quad = lane >> 4, col = lane & 15;
  const int wx = blockIdx.x, wy = blockIdx.y, b = blockIdx.z;
  const int h0 = wy * 16, w0 = wx * 16;

  // init constant rows 12..15 of both buffers (disjoint from per-head rows 0..11)
  for (int i = tid; i < 2*4*264; i += 256){
    int buf = i / (4*264), j = i % (4*264);
    int r = 12 + j / 264, cc = j % 264;
    short v = (r == 15) ? (short)0x3F80 : (short)0;
    ks[buf][r*264 + cc] = v; vs[buf][r*264 + cc] = v;
  }

  // B fragments: X window (K=channel, N=token), loaded once, reused for all heads
  const float* xb = x + ((size_t)b * 96 << 16);
  s8v Bf[4][3];
  #pragma unroll
  for (int jt = 0; jt < 4; ++jt){
    int t0 = wave * 64 + jt * 16;
    const float* px = xb + (size_t)(h0 + (t0 >> 4)) * 256 + (w0 + col);
    #pragma unroll
    for (int kt = 0; kt < 3; ++kt){
      F8 f;
      #pragma unroll
      for (int j = 0; j < 8; ++j){
        int c = kt * 32 + quad * 8 + j;
        f.s[j] = f2bf(px[(size_t)c << 16]);
      }
      Bf[jt][kt] = f.s;
    }
  }

  for (int h = 0; h < 8; ++h){
    const int p = h & 1;
    s8v bq[4];   // q-hat B-fragments for the 4 token groups of this wave
    // ---- Q: MFMA + l2norm -> shuffle transpose into bq (registers only) ----
    {
      s8v Aq[3];
      #pragma unroll
      for (int kt = 0; kt < 3; ++kt){
        F8 f; f.i = *(const int4*)(w1 + (h*12 + col) * 96 + kt*32 + quad*8);
        Aq[kt] = f.s;
      }
      #pragma unroll
      for (int jt = 0; jt < 4; ++jt){
        f4v a = {0.f,0.f,0.f,0.f};
        #pragma unroll
        for (int kt = 0; kt < 3; ++kt) a = MFMA(Aq[kt], Bf[jt][kt], a);
        float s = (quad < 3) ? (a[0]*a[0] + a[1]*a[1] + a[2]*a[2] + a[3]*a[3]) : 0.f;
        s += __shfl_xor(s, 16, 64); s += __shfl_xor(s, 32, 64);
        float rq = rsqrtf(s);
        float q0 = a[0]*rq, q1 = a[1]*rq, q2 = a[2]*rq, q3 = a[3]*rq;
        // B[k=quad*8+j][t=col]: k<=11 -> q_norm[k][t]; k==12 -> 1.0; else 0
        int s0 = (quad == 0) ? col        : (32 + col);  // src lane for j=0..3
        int s1 = (quad == 0) ? (16 + col) : (32 + col);  // src lane for j=4..7
        float v0 = __shfl(q0, s0, 64), v1 = __shfl(q1, s0, 64);
        float v2 = __shfl(q2, s0, 64), v3 = __shfl(q3, s0, 64);
        float w4 = __shfl(q0, s1, 64), w5 = __shfl(q1, s1, 64);
        float w6 = __shfl(q2, s1, 64), w7 = __shfl(q3, s1, 64);
        F8 f;
        bool lo = (quad < 2);
        f.s[0] = lo ? f2bf(v0) : (short)0;
        f.s[1] = lo ? f2bf(v1) : (short)0;
        f.s[2] = lo ? f2bf(v2) : (short)0;
        f.s[3] = lo ? f2bf(v3) : (short)0;
        f.s[4] = (quad == 0) ? f2bf(w4) : ((quad == 1) ? (short)0x3F80 : (short)0);
        f.s[5] = (quad == 0) ? f2bf(w5) : (short)0;
        f.s[6] = (quad == 0) ? f2bf(w6) : (short)0;
        f.s[7] = (quad == 0) ? f2bf(w7) : (short)0;
        bq[jt] = f.s;
      }
    }
    // ---- K: MFMA + l2norm -> ks scatter ----
    {
      s8v Ak[3];
      #pragma unroll
      for (int kt = 0; kt < 3; ++kt){
        F8 f; f.i = *(const int4*)(w1 + (96 + h*12 + col) * 96 + kt*32 + quad*8);
        Ak[kt] = f.s;
      }
      #pragma unroll
      for (int jt = 0; jt < 4; ++jt){
        f4v a = {0.f,0.f,0.f,0.f};
        #pragma unroll
        for (int kt = 0; kt < 3; ++kt) a = MFMA(Ak[kt], Bf[jt][kt], a);
        float s = (quad < 3) ? (a[0]*a[0] + a[1]*a[1] + a[2]*a[2] + a[3]*a[3]) : 0.f;
        s += __shfl_xor(s, 16, 64); s += __shfl_xor(s, 32, 64);
        float rk = rsqrtf(s);
        if (quad < 3){
          int t = wave*64 + jt*16 + col;
          #pragma unroll
          for (int r = 0; r < 4; ++r) ks[p][(quad*4 + r)*264 + t] = f2bf(a[r]*rk);
        }
      }
    }
    // ---- V: MFMA -> vs scatter ----
    {
      s8v Av[3];
      #pragma unroll
      for (int kt = 0; kt < 3; ++kt){
        F8 f; f.i = *(const int4*)(w1 + (192 + h*12 + col) * 96 + kt*32 + quad*8);
        Av[kt] = f.s;
      }
      #pragma unroll
      for (int jt = 0; jt < 4; ++jt){
        f4v a = {0.f,0.f,0.f,0.f};
        #pragma unroll
        for (int kt = 0; kt < 3; ++kt) a = MFMA(Av[kt], Bf[jt][kt], a);
        if (quad < 3){
          int t = wave*64 + jt*16 + col;
          #pragma unroll
          for (int r = 0; r < 4; ++r) vs[p][(quad*4 + r)*264 + t] = f2bf(a[r]);
        }
      }
    }
    __syncthreads();   // the ONE barrier per head: ks/vs buffer p complete

    // ---- kv (all waves, redundant): kv[m][c] = sum_n ks[m][n] vs[c][n] ----
    f4v kvv = {0.f,0.f,0.f,0.f};
    #pragma unroll
    for (int kk = 0; kk < 8; ++kk){
      F8 a, bv;
      a.i  = *(const int4*)&ks[p][col*264 + kk*32 + quad*8];
      bv.i = *(const int4*)&vs[p][col*264 + kk*32 + quad*8];
      kvv = MFMA(a.s, bv.s, kvv);
    }
    // kvv[r] = kv[quad*4+r][col]. Build A-frag A[c'][k]: k<=11 -> kv[k][cc];
    // k==12 -> kv[15][cc] (vsum; for c'==12 it's kv[15][15]=256); k>=13 -> 0.
    F8 fa;
    {
      int cc = (col == 12) ? 15 : col;
      int l0 = ((quad << 1) << 4) | cc;
      int l1 = (((quad << 1) + 1) << 4) | cc;
      float v;
      v = __shfl(kvv[0], l0 & 63, 64); fa.s[0] = f2bf((quad < 2) ? v : 0.f);
      v = __shfl(kvv[1], l0 & 63, 64); fa.s[1] = f2bf((quad < 2) ? v : 0.f);
      v = __shfl(kvv[2], l0 & 63, 64); fa.s[2] = f2bf((quad < 2) ? v : 0.f);
      v = __shfl(kvv[3], l0 & 63, 64); fa.s[3] = f2bf((quad < 2) ? v : 0.f);
      float v0  = __shfl(kvv[0], l1 & 63, 64);
      float v15 = __shfl(kvv[3], 48 | cc, 64);
      fa.s[4] = f2bf((quad == 0) ? v0 : ((quad == 1) ? v15 : 0.f));
      v = __shfl(kvv[1], l1 & 63, 64); fa.s[5] = f2bf((quad == 0) ? v : 0.f);
      v = __shfl(kvv[2], l1 & 63, 64); fa.s[6] = f2bf((quad == 0) ? v : 0.f);
      v = __shfl(kvv[3], l1 & 63, 64); fa.s[7] = f2bf((quad == 0) ? v : 0.f);
    }
    // ---- final: D2 = kvT x qhat; row 12 = denominator (includes the +256) ----
    #pragma unroll
    for (int jt = 0; jt < 4; ++jt){
      int t0 = wave*64 + jt*16;
      f4v z = {0.f,0.f,0.f,0.f};
      f4v d2 = MFMA(fa.s, bq[jt], z);
      float dot = __shfl(d2[0], 48 + col, 64);
      float tl = 1.f / dot;
      if (quad < 3){
        int pix = (h0 + (t0 >> 4)) * 256 + (w0 + col);
        short* po = outp + ((size_t)((b*8 + h) * 65536 + pix)) * 12 + quad*4;
        short4 pk; pk.x = f2bf(d2[0]*tl); pk.y = f2bf(d2[1]*tl); pk.z = f2bf(d2[2]*tl); pk.w = f2bf(d2[3]*tl);
        *(short4*)po = pk;
      }
    }
    // no trailing barrier: next head writes the other ks/vs buffer; q is in regs
  }
}

// ---- shared B-fragment loader for proj kernels (head-major padded K=128) ----
__device__ __forceinline__ void load_proj_bfrag(const short* __restrict__ outp,
                                                int b, int pixrow, int wave, int quad, int col,
                                                s8v Bf[4][4]){
  #pragma unroll
  for (int jt = 0; jt < 4; ++jt){
    int pix = pixrow + wave*64 + jt*16 + col;
    #pragma unroll
    for (int kt = 0; kt < 4; ++kt){
      int h = kt*2 + (quad >> 1);
      const short* pb = outp + ((size_t)((b*8 + h) * 65536 + pix)) * 12;
      F8L f;
      if ((quad & 1) == 0){ f.l[0] = *(const long long*)(pb);     f.l[1] = *(const long long*)(pb + 4); }
      else                { f.l[0] = *(const long long*)(pb + 8); f.l[1] = 0; }
      Bf[jt][kt] = f.s;
    }
  }
}

// pass 1: proj MFMA for BN stats only (no y write)
__global__ __launch_bounds__(256,4) void projstats_kernel(const short* __restrict__ outp,
                                                          const unsigned short* __restrict__ w2p,
                                                          float* __restrict__ stats){
  __shared__ float sld[192];
  const int tid = threadIdx.x;
  if (tid < 192) sld[tid] = 0.f;
  __syncthreads();
  const int lane = tid & 63, wave = tid >> 6;
  const int quad = lane >> 4, col = lane & 15;
  const int hrow = blockIdx.x, b = blockIdx.y;

  s8v Bf[4][4];
  load_proj_bfrag(outp, b, hrow*256, wave, quad, col, Bf);

  #pragma unroll
  for (int mt = 0; mt < 6; ++mt){
    s8v Af[4];
    #pragma unroll
    for (int kt = 0; kt < 4; ++kt){
      F8 f; f.i = *(const int4*)(w2p + (mt*16 + col)*128 + kt*32 + quad*8);
      Af[kt] = f.s;
    }
    float rs[4] = {0.f,0.f,0.f,0.f}, rss[4] = {0.f,0.f,0.f,0.f};
    #pragma unroll
    for (int jt = 0; jt < 4; ++jt){
      f4v a = {0.f,0.f,0.f,0.f};
      #pragma unroll
      for (int kt = 0; kt < 4; ++kt) a = MFMA(Af[kt], Bf[jt][kt], a);
      #pragma unroll
      for (int r = 0; r < 4; ++r){ float v = a[r]; rs[r] += v; rss[r] += v*v; }
    }
    #pragma unroll
    for (int r = 0; r < 4; ++r){
      float a1 = rs[r], a2 = rss[r];
      a1 += __shfl_xor(a1, 1, 64); a2 += __shfl_xor(a2, 1, 64);
      a1 += __shfl_xor(a1, 2, 64); a2 += __shfl_xor(a2, 2, 64);
      a1 += __shfl_xor(a1, 4, 64); a2 += __shfl_xor(a2, 4, 64);
      a1 += __shfl_xor(a1, 8, 64); a2 += __shfl_xor(a2, 8, 64);
      if (col == 0){
        int o = mt*16 + quad*4 + r;
        atomicAdd(&sld[o], a1);
        atomicAdd(&sld[96 + o], a2);
      }
    }
  }
  __syncthreads();
  if (tid < 192) atomicAdd(&stats[tid], sld[tid]);
}

// pass 2: proj MFMA + fused BN normalize, single fp32 write of final y
__global__ __launch_bounds__(256,4) void projbn_kernel(const short* __restrict__ outp,
                                                       const unsigned short* __restrict__ w2p,
                                                       const float* __restrict__ stats,
                                                       const float* __restrict__ gamma,
                                                       const float* __restrict__ beta,
                                                       float* __restrict__ y){
  __shared__ float sc[96], sh[96];
  const int tid = threadIdx.x;
  if (tid < 96){
    const float invN = 1.f / 524288.f;
    float m  = stats[tid] * invN;
    float var = stats[96 + tid] * invN - m*m;
    float s = gamma[tid] * rsqrtf(var + 1e-5f);
    sc[tid] = s; sh[tid] = beta[tid] - m * s;
  }
  __syncthreads();
  const int lane = tid & 63, wave = tid >> 6;
  const int quad = lane >> 4, col = lane & 15;
  const int hrow = blockIdx.x, b = blockIdx.y;

  s8v Bf[4][4];
  load_proj_bfrag(outp, b, hrow*256, wave, quad, col, Bf);

  float* yb = y + ((size_t)(b*96) << 16) + (size_t)hrow * 256;
  #pragma unroll
  for (int mt = 0; mt < 6; ++mt){
    s8v Af[4];
    #pragma unroll
    for (int kt = 0; kt < 4; ++kt){
      F8 f; f.i = *(const int4*)(w2p + (mt*16 + col)*128 + kt*32 + quad*8);
      Af[kt] = f.s;
    }
    #pragma unroll
    for (int jt = 0; jt < 4; ++jt){
      int n0 = wave*64 + jt*16;
      f4v a = {0.f,0.f,0.f,0.f};
      #pragma unroll
      for (int kt = 0; kt < 4; ++kt) a = MFMA(Af[kt], Bf[jt][kt], a);
      #pragma unroll
      for (int r = 0; r < 4; ++r){
        int ch = mt*16 + quad*4 + r;
        yb[((size_t)ch << 16) + n0 + col] = a[r] * sc[ch] + sh[ch];
      }
    }
  }
}

extern "C" void kernel_launch(void* const* d_in, const int* in_sizes, int n_in,
                              void* d_out, int out_size, void* d_ws, size_t ws_size,
                              hipStream_t stream){
  const float* x     = (const float*)d_in[0];
  const float* wqkv  = (const float*)d_in[1];
  const float* wproj = (const float*)d_in[2];
  const float* gamma = (const float*)d_in[3];
  const float* beta  = (const float*)d_in[4];
  char* ws = (char*)d_ws;
  unsigned short* w1  = (unsigned short*)(ws);
  unsigned short* w2p = (unsigned short*)(ws + WS_W2_OFF);
  float* stats = (float*)(ws + WS_ST_OFF);
  short* outp  = (short*)(ws + WS_OUT_OFF);
  float* y = (float*)d_out;

  hipLaunchKernelGGL(prep_kernel, dim3(64), dim3(256), 0, stream, wqkv, wproj, w1, w2p, stats);
  hipLaunchKernelGGL(attn_kernel, dim3(16, 16, 8), dim3(256), 0, stream, x, w1, outp);
  hipLaunchKernelGGL(projstats_kernel, dim3(256, 8), dim3(256), 0, stream, outp, w2p, stats);
  hipLaunchKernelGGL(projbn_kernel, dim3(256, 8), dim3(256), 0, stream, outp, w2p, stats, gamma, beta, y);
}